// Round 2
// baseline (393.649 us; speedup 1.0000x reference)
//
#include <hip/hip_runtime.h>
#include <stdint.h>

#define NB 4
#define NSEQ 2048
#define DIN 384
#define DV 384
#define NH 8
#define DH 48
#define DFF 1536
#define MTOT (NB*NSEQ)   // 8192

typedef __attribute__((ext_vector_type(8))) short bf16x8;
typedef __attribute__((ext_vector_type(4))) float f32x4;
typedef unsigned short u16;

#define SCALE 0.05103103630798287f  // 1/sqrt(384)

__device__ __forceinline__ u16 f2bf(float f) {
  unsigned u = __builtin_bit_cast(unsigned, f);
  u = (u + 0x7FFFu + ((u >> 16) & 1u)) >> 16;
  return (u16)u;
}
__device__ __forceinline__ float bf2f(u16 h) {
  unsigned u = ((unsigned)h) << 16;
  return __builtin_bit_cast(float, u);
}

// ---------------- convert f32 -> bf16 (x, y, Wq, Wk, Wv, W1, W2) ----------------
__global__ __launch_bounds__(256) void convert_k(
    const float* __restrict__ xf, const float* __restrict__ yf,
    const float* __restrict__ wq, const float* __restrict__ wk,
    const float* __restrict__ wv, const float* __restrict__ w1,
    const float* __restrict__ w2,
    u16* __restrict__ xb, u16* __restrict__ yb,
    u16* __restrict__ wqb, u16* __restrict__ wkb, u16* __restrict__ wvb,
    u16* __restrict__ w1b, u16* __restrict__ w2b) {
  long i = (long)blockIdx.x * 256 + threadIdx.x;  // 4-elem unit
  const float* src; u16* dst; long u = i;
  if      (u < 786432)  { src = xf; dst = xb; }
  else if (u < 1572864) { u -= 786432;  src = yf; dst = yb; }
  else if (u < 1609728) { u -= 1572864; src = wq; dst = wqb; }
  else if (u < 1646592) { u -= 1609728; src = wk; dst = wkb; }
  else if (u < 1683456) { u -= 1646592; src = wv; dst = wvb; }
  else if (u < 1830912) { u -= 1683456; src = w1; dst = w1b; }
  else                  { u -= 1830912; src = w2; dst = w2b; }
  float4 v = ((const float4*)src)[u];
  ushort4 o;
  o.x = f2bf(v.x); o.y = f2bf(v.y); o.z = f2bf(v.z); o.w = f2bf(v.w);
  ((ushort4*)dst)[u] = o;
}

// ---------------- generic C = A(MxK) * B(NxK)^T tile (128x128, BK=64) ----------------
// EPI: 0 = store bf16; 1 = gelu(erf) then store bf16; 2 = Cf[idx] += v (f32)
template<int EPI>
__device__ __forceinline__ void gemm_tile(const u16* __restrict__ A,
                                          const u16* __restrict__ Bw, int K,
                                          int m0, int n0, int ldc,
                                          u16* __restrict__ Cb,
                                          float* __restrict__ Cf) {
  __shared__ __align__(16) u16 Al[128][72];
  __shared__ __align__(16) u16 Bl[128][72];
  const int t = threadIdx.x;
  const int l = t & 63, w = t >> 6;
  const int wm = w >> 1, wn = w & 1;
  f32x4 acc[4][4] = {};
  const int KT = K >> 6;
  for (int kt = 0; kt < KT; ++kt) {
    const int k0 = kt * 64;
    bf16x8 ar[4], br[4];
#pragma unroll
    for (int s = 0; s < 4; ++s) {
      int u = t + 256 * s; int r = u >> 3, ch = u & 7;
      ar[s] = *(const bf16x8*)(A  + (long)(m0 + r) * K + k0 + ch * 8);
      br[s] = *(const bf16x8*)(Bw + (long)(n0 + r) * K + k0 + ch * 8);
    }
    __syncthreads();   // previous iteration's frag reads done
#pragma unroll
    for (int s = 0; s < 4; ++s) {
      int u = t + 256 * s; int r = u >> 3, ch = u & 7;
      *(bf16x8*)(&Al[r][ch * 8]) = ar[s];
      *(bf16x8*)(&Bl[r][ch * 8]) = br[s];
    }
    __syncthreads();   // staged data visible
#pragma unroll
    for (int ks = 0; ks < 2; ++ks) {
      const int kc = ks * 32 + (l >> 4) * 8;
      bf16x8 af[4], bfr[4];
#pragma unroll
      for (int mt = 0; mt < 4; ++mt)
        af[mt] = *(const bf16x8*)(&Al[wm * 64 + mt * 16 + (l & 15)][kc]);
#pragma unroll
      for (int nt = 0; nt < 4; ++nt)
        bfr[nt] = *(const bf16x8*)(&Bl[wn * 64 + nt * 16 + (l & 15)][kc]);
#pragma unroll
      for (int mt = 0; mt < 4; ++mt)
#pragma unroll
        for (int nt = 0; nt < 4; ++nt)
          acc[mt][nt] = __builtin_amdgcn_mfma_f32_16x16x32_bf16(af[mt], bfr[nt], acc[mt][nt], 0, 0, 0);
    }
  }
  // epilogue
#pragma unroll
  for (int mt = 0; mt < 4; ++mt)
#pragma unroll
    for (int nt = 0; nt < 4; ++nt)
#pragma unroll
      for (int jr = 0; jr < 4; ++jr) {
        int gm = m0 + wm * 64 + mt * 16 + (l >> 4) * 4 + jr;
        int gn = n0 + wn * 64 + nt * 16 + (l & 15);
        float v = acc[mt][nt][jr];
        long idx = (long)gm * ldc + gn;
        if (EPI == 0) {
          Cb[idx] = f2bf(v);
        } else if (EPI == 1) {
          float g = 0.5f * v * (1.0f + erff(v * 0.70710678118654752f));
          Cb[idx] = f2bf(g);
        } else {
          Cf[idx] = Cf[idx] + v;
        }
      }
}

// one launch: by in [0,9): mat = by/3 (0=Q from x, 1=K from y, 2=V from y), ntile = by%3
__global__ __launch_bounds__(256) void qkv_k(const u16* __restrict__ xb,
                                             const u16* __restrict__ yb,
                                             const u16* __restrict__ Wb,
                                             u16* __restrict__ QKVb) {
  int bx = blockIdx.x;          // 0..63 (M tiles)
  int by = blockIdx.y;          // 0..8
  int mat = by / 3, ntile = by - mat * 3;
  const u16* A = (mat == 0) ? xb : yb;
  const u16* Bw = Wb + (long)mat * (DV * DIN);
  u16* C = QKVb + (long)mat * ((long)MTOT * DV);
  gemm_tile<0>(A, Bw, DIN, bx * 128, ntile * 128, DV, C, nullptr);
}

__global__ __launch_bounds__(256) void ffn1_k(const u16* __restrict__ Ob,
                                              const u16* __restrict__ W1b,
                                              u16* __restrict__ hid) {
  gemm_tile<1>(Ob, W1b, DV, blockIdx.x * 128, blockIdx.y * 128, DFF, hid, nullptr);
}

__global__ __launch_bounds__(256) void ffn2_k(const u16* __restrict__ hid,
                                              const u16* __restrict__ W2b,
                                              float* __restrict__ Out) {
  gemm_tile<2>(hid, W2b, DFF, blockIdx.x * 128, blockIdx.y * 128, DV, nullptr, Out);
}

// ---------------- attention: one block per (b, h, 16-row q-tile) ----------------
__global__ __launch_bounds__(256) void attn_k(const u16* __restrict__ Qb,
                                              const u16* __restrict__ Kb,
                                              const u16* __restrict__ Vb,
                                              u16* __restrict__ Ob,
                                              float* __restrict__ Out) {
  __shared__ __align__(16) u16 Kl[128][72];
  __shared__ __align__(16) u16 VTl[48][136];
  __shared__ __align__(16) u16 Ql[16][72];
  __shared__ __align__(16) u16 Pl[16][136];
  __shared__ float red[4][16][2];
  __shared__ float mfin[16], isum[16];
  __shared__ float Ol[4][16][48];

  // XCD-aware swizzle: 4096 blocks, 8 XCDs, 512 contiguous per XCD
  int bx0 = blockIdx.x;
  int lg = (bx0 & 7) * 512 + (bx0 >> 3);
  int qt = lg & 127, h = (lg >> 7) & 7, b = lg >> 10;
  const int t = threadIdx.x, l = t & 63, w = t >> 6;
  const long rowbase = (long)b * NSEQ;
  const int q0 = qt * 16;
  const int hc = h * DH;   // head col offset (elems)

  // zero pads (cols 48..63), staged once
  for (int i = t; i < 128 * 16; i += 256) { int r = i >> 4, c = i & 15; Kl[r][48 + c] = 0; }
  { int r = t >> 4, c = t & 15; Ql[r][48 + c] = 0; }   // 256 threads = 16x16
  // stage Q tile (16 rows x 48 cols = 96 16B units)
  if (t < 96) {
    int r = t / 6, ch = t - r * 6;
    *(bf16x8*)(&Ql[r][ch * 8]) = *(const bf16x8*)(Qb + (rowbase + q0 + r) * DV + hc + ch * 8);
  }
  __syncthreads();

  // per-wave Q fragments (constant across both passes)
  bf16x8 qa[2];
#pragma unroll
  for (int ks = 0; ks < 2; ++ks)
    qa[ks] = *(const bf16x8*)(&Ql[l & 15][ks * 32 + (l >> 4) * 8]);

  float mL[4], sL[4];
#pragma unroll
  for (int jr = 0; jr < 4; ++jr) { mL[jr] = -1e30f; sL[jr] = 0.0f; }

  // -------- pass 1: online (max, sumexp) stats --------
  for (int c = 0; c < 16; ++c) {
    __syncthreads();
#pragma unroll
    for (int s = 0; s < 3; ++s) {
      int u = t + 256 * s; int r = u / 6, ch = u - r * 6;
      *(bf16x8*)(&Kl[r][ch * 8]) = *(const bf16x8*)(Kb + (rowbase + c * 128 + r) * DV + hc + ch * 8);
    }
    __syncthreads();
#pragma unroll
    for (int jj = 0; jj < 2; ++jj) {
      int jl = 2 * w + jj;
      f32x4 d = {};
#pragma unroll
      for (int ks = 0; ks < 2; ++ks) {
        bf16x8 kb = *(const bf16x8*)(&Kl[jl * 16 + (l & 15)][ks * 32 + (l >> 4) * 8]);
        d = __builtin_amdgcn_mfma_f32_16x16x32_bf16(qa[ks], kb, d, 0, 0, 0);
      }
#pragma unroll
      for (int jr = 0; jr < 4; ++jr) {
        float x = d[jr] * SCALE;
        float mo = mL[jr], mn = fmaxf(mo, x);
        sL[jr] = sL[jr] * __expf(mo - mn) + __expf(x - mn);
        mL[jr] = mn;
      }
    }
  }

  // reduce over 16 lanes sharing same rows, then across waves
#pragma unroll
  for (int jr = 0; jr < 4; ++jr) {
    float m = mL[jr], s = sL[jr];
#pragma unroll
    for (int off = 1; off < 16; off <<= 1) {
      float om = __shfl_xor(m, off, 64);
      float os = __shfl_xor(s, off, 64);
      float mn = fmaxf(m, om);
      s = s * __expf(m - mn) + os * __expf(om - mn);
      m = mn;
    }
    if ((l & 15) == 0) { int row = (l >> 4) * 4 + jr; red[w][row][0] = m; red[w][row][1] = s; }
  }
  __syncthreads();
  if (t < 16) {
    float m = red[0][t][0];
    for (int ww = 1; ww < 4; ++ww) m = fmaxf(m, red[ww][t][0]);
    float s = 0.0f;
    for (int ww = 0; ww < 4; ++ww) s += red[ww][t][1] * __expf(red[ww][t][0] - m);
    mfin[t] = m; isum[t] = 1.0f / s;
  }
  __syncthreads();
  float mrow[4], irow[4];
#pragma unroll
  for (int jr = 0; jr < 4; ++jr) {
    int row = (l >> 4) * 4 + jr;
    mrow[jr] = mfin[row]; irow[jr] = isum[row];
  }

  // -------- pass 2: P = softmax, O += P*V --------
  f32x4 oacc[3] = {};
  for (int c = 0; c < 16; ++c) {
    __syncthreads();
#pragma unroll
    for (int s = 0; s < 3; ++s) {
      int u = t + 256 * s; int r = u / 6, ch = u - r * 6;
      *(bf16x8*)(&Kl[r][ch * 8]) = *(const bf16x8*)(Kb + (rowbase + c * 128 + r) * DV + hc + ch * 8);
    }
    {  // stage V transposed: VTl[d][r]
      int r = t >> 1, half = t & 1;
#pragma unroll
      for (int uu = 0; uu < 3; ++uu) {
        bf16x8 v = *(const bf16x8*)(Vb + (rowbase + c * 128 + r) * DV + hc + half * 24 + uu * 8);
#pragma unroll
        for (int e = 0; e < 8; ++e) VTl[half * 24 + uu * 8 + e][r] = (u16)v[e];
      }
    }
    __syncthreads();
#pragma unroll
    for (int jj = 0; jj < 2; ++jj) {
      int jl = 2 * w + jj;
      f32x4 d = {};
#pragma unroll
      for (int ks = 0; ks < 2; ++ks) {
        bf16x8 kb = *(const bf16x8*)(&Kl[jl * 16 + (l & 15)][ks * 32 + (l >> 4) * 8]);
        d = __builtin_amdgcn_mfma_f32_16x16x32_bf16(qa[ks], kb, d, 0, 0, 0);
      }
#pragma unroll
      for (int jr = 0; jr < 4; ++jr) {
        float x = d[jr] * SCALE;
        float p = __expf(x - mrow[jr]) * irow[jr];
        Pl[(l >> 4) * 4 + jr][jl * 16 + (l & 15)] = f2bf(p);
      }
    }
    // PV: wave w consumes exactly the P columns it wrote (32w..32w+31)
    bf16x8 pa = *(const bf16x8*)(&Pl[l & 15][w * 32 + (l >> 4) * 8]);
#pragma unroll
    for (int dt = 0; dt < 3; ++dt) {
      bf16x8 vb2 = *(const bf16x8*)(&VTl[dt * 16 + (l & 15)][w * 32 + (l >> 4) * 8]);
      oacc[dt] = __builtin_amdgcn_mfma_f32_16x16x32_bf16(pa, vb2, oacc[dt], 0, 0, 0);
    }
  }

  // combine 4 wave-partials, add Q residual, write outputs
#pragma unroll
  for (int dt = 0; dt < 3; ++dt)
#pragma unroll
    for (int jr = 0; jr < 4; ++jr)
      Ol[w][(l >> 4) * 4 + jr][dt * 16 + (l & 15)] = oacc[dt][jr];
  __syncthreads();
  for (int i = t; i < 768; i += 256) {
    int row = i / 48, dd = i - row * 48;
    float s = Ol[0][row][dd] + Ol[1][row][dd] + Ol[2][row][dd] + Ol[3][row][dd];
    long gr = rowbase + q0 + row;
    float q = bf2f(Qb[gr * DV + hc + dd]);
    float val = q + s;
    Out[gr * DV + hc + dd] = val;
    Ob[gr * DV + hc + dd] = f2bf(val);
  }
}

// ---------------- launcher ----------------
extern "C" void kernel_launch(void* const* d_in, const int* in_sizes, int n_in,
                              void* d_out, int out_size, void* d_ws, size_t ws_size,
                              hipStream_t stream) {
  const float* xf = (const float*)d_in[0];
  const float* yf = (const float*)d_in[1];
  const float* wq = (const float*)d_in[2];
  const float* wk = (const float*)d_in[3];
  const float* wv = (const float*)d_in[4];
  const float* w1 = (const float*)d_in[5];
  const float* w2 = (const float*)d_in[6];
  float* Out = (float*)d_out;

  char* ws = (char*)d_ws;
  // layout (bytes)
  u16* xb   = (u16*)(ws + 0);          // 6291456
  u16* yb   = (u16*)(ws + 6291456);    // 6291456
  u16* QKVb = (u16*)(ws + 12582912);   // Q,K,V contiguous, 3*6291456
  u16* Qb   = QKVb;
  u16* Kb   = (u16*)(ws + 18874368);
  u16* Vb   = (u16*)(ws + 25165824);
  u16* Ob   = (u16*)(ws + 31457280);   // 6291456
  u16* Wqb  = (u16*)(ws + 37748736);   // 294912 * 3 (Wq,Wk,Wv contiguous)
  u16* Wkb  = (u16*)(ws + 38043648);
  u16* Wvb  = (u16*)(ws + 38338560);
  u16* W1b  = (u16*)(ws + 38633472);   // 1179648
  u16* W2b  = (u16*)(ws + 39813120);   // 1179648
  u16* hid  = (u16*)(ws + 0);          // 25165824, aliases xb/yb/Qb/Kb (dead by FFN1)

  convert_k<<<7728, 256, 0, stream>>>(xf, yf, wq, wk, wv, w1, w2,
                                      xb, yb, Wqb, Wkb, Wvb, W1b, W2b);
  qkv_k<<<dim3(64, 9), 256, 0, stream>>>(xb, yb, Wqb, QKVb);
  attn_k<<<4096, 256, 0, stream>>>(Qb, Kb, Vb, Ob, Out);
  ffn1_k<<<dim3(64, 12), 256, 0, stream>>>(Ob, W1b, hid);
  ffn2_k<<<dim3(64, 3), 256, 0, stream>>>(hid, W2b, Out);
}

// Round 4
// 273.944 us; speedup vs baseline: 1.4370x; 1.4370x over previous
//
#include <hip/hip_runtime.h>
#include <stdint.h>

#define NB 4
#define NSEQ 2048
#define DIN 384
#define DV 384
#define NH 8
#define DH 48
#define DFF 1536
#define MTOT (NB*NSEQ)   // 8192
#define QBLK 64

typedef __attribute__((ext_vector_type(8))) short bf16x8;
typedef __attribute__((ext_vector_type(4))) float f32x4;
typedef unsigned short u16;

#define SCALE 0.05103103630798287f  // 1/sqrt(384)

__device__ __forceinline__ u16 f2bf(float f) {
  unsigned u = __builtin_bit_cast(unsigned, f);
  u = (u + 0x7FFFu + ((u >> 16) & 1u)) >> 16;
  return (u16)u;
}
__device__ __forceinline__ float bf2f(u16 h) {
  unsigned u = ((unsigned)h) << 16;
  return __builtin_bit_cast(float, u);
}

// async global->LDS, 16B per lane; LDS dest must be lane-linear (base + lane*16)
__device__ __forceinline__ void gload16(const u16* g, u16* l) {
  __builtin_amdgcn_global_load_lds(
      (const __attribute__((address_space(1))) void*)g,
      (__attribute__((address_space(3))) void*)l, 16, 0, 0);
}

// ---------------- convert f32 -> bf16 (x, y, Wq, Wk, Wv, W1, W2) ----------------
__global__ __launch_bounds__(256) void convert_k(
    const float* __restrict__ xf, const float* __restrict__ yf,
    const float* __restrict__ wq, const float* __restrict__ wk,
    const float* __restrict__ wv, const float* __restrict__ w1,
    const float* __restrict__ w2,
    u16* __restrict__ xb, u16* __restrict__ yb,
    u16* __restrict__ wqb, u16* __restrict__ wkb, u16* __restrict__ wvb,
    u16* __restrict__ w1b, u16* __restrict__ w2b) {
  long i = (long)blockIdx.x * 256 + threadIdx.x;  // 4-elem unit
  const float* src; u16* dst; long u = i;
  if      (u < 786432)  { src = xf; dst = xb; }
  else if (u < 1572864) { u -= 786432;  src = yf; dst = yb; }
  else if (u < 1609728) { u -= 1572864; src = wq; dst = wqb; }
  else if (u < 1646592) { u -= 1609728; src = wk; dst = wkb; }
  else if (u < 1683456) { u -= 1646592; src = wv; dst = wvb; }
  else if (u < 1830912) { u -= 1683456; src = w1; dst = w1b; }
  else                  { u -= 1830912; src = w2; dst = w2b; }
  float4 v = ((const float4*)src)[u];
  ushort4 o;
  o.x = f2bf(v.x); o.y = f2bf(v.y); o.z = f2bf(v.z); o.w = f2bf(v.w);
  ((ushort4*)dst)[u] = o;
}

// ---------------- generic C = A(MxK) * B(NxK)^T tile (128x128, BK=64) ----------------
// global_load_lds staging: linear LDS [128][64] u16, source col-slot pre-swizzled
// (slot ^ (row&7)), frag reads apply the same XOR.  EPI: 0 = store bf16;
// 1 = gelu(erf) then bf16; 2 = Cf[idx] += v (f32)
template<int EPI>
__device__ __forceinline__ void gemm_tile(const u16* __restrict__ A,
                                          const u16* __restrict__ Bw, int K,
                                          int m0, int n0, int ldc,
                                          u16* __restrict__ Cb,
                                          float* __restrict__ Cf) {
  __shared__ __align__(16) u16 Al[128 * 64];
  __shared__ __align__(16) u16 Bl[128 * 64];
  const int t = threadIdx.x;
  const int l = t & 63, w = t >> 6;
  const int g = l >> 4, nn = l & 15;
  const int wm = w >> 1, wn = w & 1;
  f32x4 acc[4][4] = {};
  const int KT = K >> 6;
  for (int kt = 0; kt < KT; ++kt) {
    const int k0 = kt * 64;
    __syncthreads();   // previous iteration's frag reads done
#pragma unroll
    for (int s = 0; s < 4; ++s) {
      int u = t + 256 * s; int r = u >> 3, ch = u & 7;
      int csw = (ch ^ (r & 7)) * 8;     // inverse-swizzled source column
      gload16(A  + (long)(m0 + r) * K + k0 + csw, Al + u * 8);
      gload16(Bw + (long)(n0 + r) * K + k0 + csw, Bl + u * 8);
    }
    __syncthreads();   // vmcnt drained, staged data visible
#pragma unroll
    for (int ks = 0; ks < 2; ++ks) {
      const int slot = ((ks * 4 + g) ^ (nn & 7)) * 8;
      bf16x8 af[4], bfr[4];
#pragma unroll
      for (int mt = 0; mt < 4; ++mt)
        af[mt] = *(const bf16x8*)(Al + (wm * 64 + mt * 16 + nn) * 64 + slot);
#pragma unroll
      for (int nt = 0; nt < 4; ++nt)
        bfr[nt] = *(const bf16x8*)(Bl + (wn * 64 + nt * 16 + nn) * 64 + slot);
#pragma unroll
      for (int mt = 0; mt < 4; ++mt)
#pragma unroll
        for (int nt = 0; nt < 4; ++nt)
          acc[mt][nt] = __builtin_amdgcn_mfma_f32_16x16x32_bf16(af[mt], bfr[nt], acc[mt][nt], 0, 0, 0);
    }
  }
  // epilogue
#pragma unroll
  for (int mt = 0; mt < 4; ++mt)
#pragma unroll
    for (int nt = 0; nt < 4; ++nt)
#pragma unroll
      for (int jr = 0; jr < 4; ++jr) {
        int gm = m0 + wm * 64 + mt * 16 + g * 4 + jr;
        int gn = n0 + wn * 64 + nt * 16 + nn;
        float v = acc[mt][nt][jr];
        long idx = (long)gm * ldc + gn;
        if (EPI == 0) {
          Cb[idx] = f2bf(v);
        } else if (EPI == 1) {
          float gg = 0.5f * v * (1.0f + erff(v * 0.70710678118654752f));
          Cb[idx] = f2bf(gg);
        } else {
          Cf[idx] = Cf[idx] + v;
        }
      }
}

// one launch: by in [0,9): mat = by/3 (0=Q from x, 1=K from y, 2=V from y), ntile = by%3
__global__ __launch_bounds__(256) void qkv_k(const u16* __restrict__ xb,
                                             const u16* __restrict__ yb,
                                             const u16* __restrict__ Wb,
                                             u16* __restrict__ QKVb) {
  int bx = blockIdx.x;          // 0..63 (M tiles)
  int by = blockIdx.y;          // 0..8
  int mat = by / 3, ntile = by - mat * 3;
  const u16* A = (mat == 0) ? xb : yb;
  const u16* Bw = Wb + (long)mat * (DV * DIN);
  u16* C = QKVb + (long)mat * ((long)MTOT * DV);
  gemm_tile<0>(A, Bw, DIN, bx * 128, ntile * 128, DV, C, nullptr);
}

__global__ __launch_bounds__(256) void ffn1_k(const u16* __restrict__ Ob,
                                              const u16* __restrict__ W1b,
                                              u16* __restrict__ hid) {
  gemm_tile<1>(Ob, W1b, DV, blockIdx.x * 128, blockIdx.y * 128, DFF, hid, nullptr);
}

__global__ __launch_bounds__(256) void ffn2_k(const u16* __restrict__ hid,
                                              const u16* __restrict__ W2b,
                                              float* __restrict__ Out) {
  gemm_tile<2>(hid, W2b, DFF, blockIdx.x * 128, blockIdx.y * 128, DV, nullptr, Out);
}

// ---------------- single-pass flash attention ----------------
// 1024 blocks = (b,h,64-row q-tile); 4 waves, each owns a 16-row stripe.
// K,V^T,P in LDS, power-of-2 strides + XOR-((row&7)<<3 u16) swizzle both sides.
__global__ __launch_bounds__(256) void attn_k(const u16* __restrict__ Qb,
                                              const u16* __restrict__ Kb,
                                              const u16* __restrict__ Vb,
                                              u16* __restrict__ Ob,
                                              float* __restrict__ Out) {
  __shared__ __align__(16) u16 Kl[128 * 64];    // [k-row][64 d-cols], swizzled, 16KB
  __shared__ __align__(16) u16 VTl[48 * 128];   // [d][k], swizzled, 12KB
  __shared__ __align__(16) u16 Pl[64 * 128];    // [q][k], swizzled, 16KB (Q scratch first)

  int bx0 = blockIdx.x;
  int lg = (bx0 & 7) * 128 + (bx0 >> 3);        // XCD swizzle (1024 = 8*128, bijective)
  int qt = lg & 31, h = (lg >> 5) & 7, b = lg >> 8;
  const int t = threadIdx.x, l = t & 63, w = t >> 6;
  const int g = l >> 4, n = l & 15;
  const long rowbase = (long)b * NSEQ;
  const int q0 = qt * QBLK;
  const int hc = h * DH;

  // ---- stage scaled Q into Pl scratch (unswizzled [64][64]) + zero pads
  for (int i = t; i < 384; i += 256) {
    int r = i / 6, ch = i - r * 6;
    bf16x8 v = *(const bf16x8*)(Qb + (rowbase + q0 + r) * DV + hc + ch * 8);
    bf16x8 sv;
#pragma unroll
    for (int e = 0; e < 8; ++e) sv[e] = (short)f2bf(bf2f((u16)v[e]) * SCALE);
    *(bf16x8*)(Pl + r * 64 + ch * 8) = sv;
  }
  if (t < 128) {
    int r = t >> 1;
    bf16x8 z = {};
    *(bf16x8*)(Pl + r * 64 + 48 + (t & 1) * 8) = z;
  }
  {  // zero Kl pad slots (raw slots 6,7 at swizzled positions) — written once
    int r = t >> 1; int zs = 6 + (t & 1);
    bf16x8 z = {};
    *(bf16x8*)(Kl + r * 64 + ((zs ^ (r & 7)) * 8)) = z;
  }
  __syncthreads();

  // per-wave Q fragments (A-frag: row = stripe-local q = n, k = 32ks + 8g)
  bf16x8 qa[2];
#pragma unroll
  for (int ks = 0; ks < 2; ++ks)
    qa[ks] = *(const bf16x8*)(Pl + (w * 16 + n) * 64 + ks * 32 + g * 8);

  float mL[4], sL[4];
#pragma unroll
  for (int jr = 0; jr < 4; ++jr) { mL[jr] = -1e30f; sL[jr] = 0.0f; }
  f32x4 oacc[3] = {};

  for (int c = 0; c < 16; ++c) {
    __syncthreads();   // prev chunk LDS reads done (also protects qa/Pl scratch on c=0)
    // stage K chunk (128 rows x 48 cols), swizzled slots
    for (int i = t; i < 768; i += 256) {
      int r = i / 6, ch = i - r * 6;
      bf16x8 v = *(const bf16x8*)(Kb + (rowbase + c * 128 + r) * DV + hc + ch * 8);
      *(bf16x8*)(Kl + r * 64 + ((ch ^ (r & 7)) * 8)) = v;
    }
    // stage V transposed: 4-row packs, short4 writes, swizzled
    if (t < 192) {
      int q = t & 31, ch = t >> 5;
      const u16* vbase = Vb + (rowbase + c * 128 + 4 * q) * DV + hc + ch * 8;
      bf16x8 v0 = *(const bf16x8*)(vbase);
      bf16x8 v1 = *(const bf16x8*)(vbase + DV);
      bf16x8 v2 = *(const bf16x8*)(vbase + 2 * DV);
      bf16x8 v3 = *(const bf16x8*)(vbase + 3 * DV);
#pragma unroll
      for (int e = 0; e < 8; ++e) {
        short4 pk; pk.x = v0[e]; pk.y = v1[e]; pk.z = v2[e]; pk.w = v3[e];
        int d = ch * 8 + e;
        *(short4*)(VTl + ((d * 128 + 4 * q) ^ (e << 3))) = pk;
      }
    }
    __syncthreads();

    // QK^T: wave computes its 16 q-rows x 128 k-cols (8 jl tiles)
    f32x4 sc[8];
#pragma unroll
    for (int jl = 0; jl < 8; ++jl) {
      f32x4 a = {};
#pragma unroll
      for (int ks = 0; ks < 2; ++ks) {
        bf16x8 kb = *(const bf16x8*)(Kl + (jl * 16 + n) * 64 + (((ks * 4 + g) ^ (n & 7)) * 8));
        a = __builtin_amdgcn_mfma_f32_16x16x32_bf16(qa[ks], kb, a, 0, 0, 0);
      }
      sc[jl] = a;
    }

    // online softmax (rows 4g+jr), P->LDS (bf16, swizzled), O rescale
#pragma unroll
    for (int jr = 0; jr < 4; ++jr) {
      float mx = sc[0][jr];
#pragma unroll
      for (int jl = 1; jl < 8; ++jl) mx = fmaxf(mx, sc[jl][jr]);
      mx = fmaxf(mx, __shfl_xor(mx, 1, 64));
      mx = fmaxf(mx, __shfl_xor(mx, 2, 64));
      mx = fmaxf(mx, __shfl_xor(mx, 4, 64));
      mx = fmaxf(mx, __shfl_xor(mx, 8, 64));
      float mn = fmaxf(mL[jr], mx);
      float scl = __expf(mL[jr] - mn);
      mL[jr] = mn;
      float rs = 0.0f;
      const int prow = w * 16 + 4 * g + jr;
      const int pswz = ((4 * g + jr) & 7) << 3;
#pragma unroll
      for (int jl = 0; jl < 8; ++jl) {
        float p = __expf(sc[jl][jr] - mn);
        rs += p;
        Pl[(prow * 128 + jl * 16 + n) ^ pswz] = f2bf(p);
      }
      rs += __shfl_xor(rs, 1, 64);
      rs += __shfl_xor(rs, 2, 64);
      rs += __shfl_xor(rs, 4, 64);
      rs += __shfl_xor(rs, 8, 64);
      sL[jr] = sL[jr] * scl + rs;
#pragma unroll
      for (int dt = 0; dt < 3; ++dt) oacc[dt][jr] *= scl;
    }

    // PV: own-wave P rows (lgkmcnt dependency, no barrier needed)
#pragma unroll
    for (int ks4 = 0; ks4 < 4; ++ks4) {
      const int slot = ((ks4 * 4 + g) ^ (n & 7)) * 8;
      bf16x8 pa = *(const bf16x8*)(Pl + (w * 16 + n) * 128 + slot);
#pragma unroll
      for (int dt = 0; dt < 3; ++dt) {
        bf16x8 vb = *(const bf16x8*)(VTl + (dt * 16 + n) * 128 + slot);
        oacc[dt] = __builtin_amdgcn_mfma_f32_16x16x32_bf16(pa, vb, oacc[dt], 0, 0, 0);
      }
    }
  }

  // epilogue: normalize, add (unscaled) Q residual, write f32 + bf16
#pragma unroll
  for (int jr = 0; jr < 4; ++jr) {
    float inv = 1.0f / sL[jr];
    long gr = rowbase + q0 + w * 16 + 4 * g + jr;
#pragma unroll
    for (int dt = 0; dt < 3; ++dt) {
      int col = hc + dt * 16 + n;
      float val = oacc[dt][jr] * inv;
      float q = bf2f(Qb[gr * DV + col]);
      float o = q + val;
      Out[gr * DV + col] = o;
      Ob[gr * DV + col] = f2bf(o);
    }
  }
}

// ---------------- launcher ----------------
extern "C" void kernel_launch(void* const* d_in, const int* in_sizes, int n_in,
                              void* d_out, int out_size, void* d_ws, size_t ws_size,
                              hipStream_t stream) {
  const float* xf = (const float*)d_in[0];
  const float* yf = (const float*)d_in[1];
  const float* wq = (const float*)d_in[2];
  const float* wk = (const float*)d_in[3];
  const float* wv = (const float*)d_in[4];
  const float* w1 = (const float*)d_in[5];
  const float* w2 = (const float*)d_in[6];
  float* Out = (float*)d_out;

  char* ws = (char*)d_ws;
  u16* xb   = (u16*)(ws + 0);          // 6291456
  u16* yb   = (u16*)(ws + 6291456);    // 6291456
  u16* QKVb = (u16*)(ws + 12582912);   // Q,K,V contiguous, 3*6291456
  u16* Qb   = QKVb;
  u16* Kb   = (u16*)(ws + 18874368);
  u16* Vb   = (u16*)(ws + 25165824);
  u16* Ob   = (u16*)(ws + 31457280);   // 6291456
  u16* Wqb  = (u16*)(ws + 37748736);   // 294912*3 (Wq,Wk,Wv contiguous)
  u16* W1b  = (u16*)(ws + 38633472);   // 1179648
  u16* W2b  = (u16*)(ws + 39813120);   // 1179648
  u16* hid  = (u16*)(ws + 0);          // 25165824, aliases xb/yb/Qb/Kb (dead by FFN1)
  u16* Wkb  = (u16*)(ws + 38043648);
  u16* Wvb  = (u16*)(ws + 38338560);

  convert_k<<<7728, 256, 0, stream>>>(xf, yf, wq, wk, wv, w1, w2,
                                      xb, yb, Wqb, Wkb, Wvb, W1b, W2b);
  qkv_k<<<dim3(64, 9), 256, 0, stream>>>(xb, yb, Wqb, QKVb);
  attn_k<<<1024, 256, 0, stream>>>(Qb, Kb, Vb, Ob, Out);
  ffn1_k<<<dim3(64, 12), 256, 0, stream>>>(Ob, W1b, hid);
  ffn2_k<<<dim3(64, 3), 256, 0, stream>>>(hid, W2b, Out);
}

// Round 5
// 231.905 us; speedup vs baseline: 1.6975x; 1.1813x over previous
//
#include <hip/hip_runtime.h>
#include <stdint.h>

#define NB 4
#define NSEQ 2048
#define DIN 384
#define DV 384
#define NH 8
#define DH 48
#define DFF 1536
#define MTOT (NB*NSEQ)   // 8192
#define QBLK 128

typedef __attribute__((ext_vector_type(8))) short bf16x8;
typedef __attribute__((ext_vector_type(4))) float f32x4;
typedef unsigned short u16;

#define SCALE 0.05103103630798287f  // 1/sqrt(384)

__device__ __forceinline__ u16 f2bf(float f) {
  unsigned u = __builtin_bit_cast(unsigned, f);
  u = (u + 0x7FFFu + ((u >> 16) & 1u)) >> 16;
  return (u16)u;
}
__device__ __forceinline__ float bf2f(u16 h) {
  unsigned u = ((unsigned)h) << 16;
  return __builtin_bit_cast(float, u);
}

// async global->LDS, 16B per lane; LDS dest must be lane-linear (base + lane*16)
__device__ __forceinline__ void gload16(const u16* g, u16* l) {
  __builtin_amdgcn_global_load_lds(
      (const __attribute__((address_space(1))) void*)g,
      (__attribute__((address_space(3))) void*)l, 16, 0, 0);
}

// ---------------- convert f32 -> bf16 (x, y, Wq, Wk, Wv, W1, W2) ----------------
__global__ __launch_bounds__(256) void convert_k(
    const float* __restrict__ xf, const float* __restrict__ yf,
    const float* __restrict__ wq, const float* __restrict__ wk,
    const float* __restrict__ wv, const float* __restrict__ w1,
    const float* __restrict__ w2,
    u16* __restrict__ xb, u16* __restrict__ yb,
    u16* __restrict__ wqb, u16* __restrict__ wkb, u16* __restrict__ wvb,
    u16* __restrict__ w1b, u16* __restrict__ w2b) {
  long i = (long)blockIdx.x * 256 + threadIdx.x;  // 4-elem unit
  const float* src; u16* dst; long u = i;
  if      (u < 786432)  { src = xf; dst = xb; }
  else if (u < 1572864) { u -= 786432;  src = yf; dst = yb; }
  else if (u < 1609728) { u -= 1572864; src = wq; dst = wqb; }
  else if (u < 1646592) { u -= 1609728; src = wk; dst = wkb; }
  else if (u < 1683456) { u -= 1646592; src = wv; dst = wvb; }
  else if (u < 1830912) { u -= 1683456; src = w1; dst = w1b; }
  else                  { u -= 1830912; src = w2; dst = w2b; }
  float4 v = ((const float4*)src)[u];
  ushort4 o;
  o.x = f2bf(v.x); o.y = f2bf(v.y); o.z = f2bf(v.z); o.w = f2bf(v.w);
  ((ushort4*)dst)[u] = o;
}

// ---------------- generic C = A(MxK) * B(NxK)^T tile (128x128, BK=64) ----------------
// global_load_lds staging: linear LDS [128][64] u16, source col-slot pre-swizzled
// (slot ^ (row&7)), frag reads apply the same XOR.  EPI: 0 = store bf16;
// 1 = gelu(erf) then bf16; 2 = Cf[idx] += v (f32)
template<int EPI>
__device__ __forceinline__ void gemm_tile(const u16* __restrict__ A,
                                          const u16* __restrict__ Bw, int K,
                                          int m0, int n0, int ldc,
                                          u16* __restrict__ Cb,
                                          float* __restrict__ Cf) {
  __shared__ __align__(16) u16 Al[128 * 64];
  __shared__ __align__(16) u16 Bl[128 * 64];
  const int t = threadIdx.x;
  const int l = t & 63, w = t >> 6;
  const int g = l >> 4, nn = l & 15;
  const int wm = w >> 1, wn = w & 1;
  f32x4 acc[4][4] = {};
  const int KT = K >> 6;
  for (int kt = 0; kt < KT; ++kt) {
    const int k0 = kt * 64;
    __syncthreads();   // previous iteration's frag reads done
#pragma unroll
    for (int s = 0; s < 4; ++s) {
      int u = t + 256 * s; int r = u >> 3, ch = u & 7;
      int csw = (ch ^ (r & 7)) * 8;     // inverse-swizzled source column
      gload16(A  + (long)(m0 + r) * K + k0 + csw, Al + u * 8);
      gload16(Bw + (long)(n0 + r) * K + k0 + csw, Bl + u * 8);
    }
    __syncthreads();   // vmcnt drained, staged data visible
#pragma unroll
    for (int ks = 0; ks < 2; ++ks) {
      const int slot = ((ks * 4 + g) ^ (nn & 7)) * 8;
      bf16x8 af[4], bfr[4];
#pragma unroll
      for (int mt = 0; mt < 4; ++mt)
        af[mt] = *(const bf16x8*)(Al + (wm * 64 + mt * 16 + nn) * 64 + slot);
#pragma unroll
      for (int nt = 0; nt < 4; ++nt)
        bfr[nt] = *(const bf16x8*)(Bl + (wn * 64 + nt * 16 + nn) * 64 + slot);
#pragma unroll
      for (int mt = 0; mt < 4; ++mt)
#pragma unroll
        for (int nt = 0; nt < 4; ++nt)
          acc[mt][nt] = __builtin_amdgcn_mfma_f32_16x16x32_bf16(af[mt], bfr[nt], acc[mt][nt], 0, 0, 0);
    }
  }
  // epilogue
#pragma unroll
  for (int mt = 0; mt < 4; ++mt)
#pragma unroll
    for (int nt = 0; nt < 4; ++nt)
#pragma unroll
      for (int jr = 0; jr < 4; ++jr) {
        int gm = m0 + wm * 64 + mt * 16 + g * 4 + jr;
        int gn = n0 + wn * 64 + nt * 16 + nn;
        float v = acc[mt][nt][jr];
        long idx = (long)gm * ldc + gn;
        if (EPI == 0) {
          Cb[idx] = f2bf(v);
        } else if (EPI == 1) {
          float gg = 0.5f * v * (1.0f + erff(v * 0.70710678118654752f));
          Cb[idx] = f2bf(gg);
        } else {
          Cf[idx] = Cf[idx] + v;
        }
      }
}

// one launch: by in [0,9): mat = by/3 (0=Q from x, 1=K from y, 2=V from y), ntile = by%3
__global__ __launch_bounds__(256) void qkv_k(const u16* __restrict__ xb,
                                             const u16* __restrict__ yb,
                                             const u16* __restrict__ Wb,
                                             u16* __restrict__ QKVb) {
  int bx = blockIdx.x;          // 0..63 (M tiles)
  int by = blockIdx.y;          // 0..8
  int mat = by / 3, ntile = by - mat * 3;
  const u16* A = (mat == 0) ? xb : yb;
  const u16* Bw = Wb + (long)mat * (DV * DIN);
  u16* C = QKVb + (long)mat * ((long)MTOT * DV);
  gemm_tile<0>(A, Bw, DIN, bx * 128, ntile * 128, DV, C, nullptr);
}

__global__ __launch_bounds__(256) void ffn1_k(const u16* __restrict__ Ob,
                                              const u16* __restrict__ W1b,
                                              u16* __restrict__ hid) {
  gemm_tile<1>(Ob, W1b, DV, blockIdx.x * 128, blockIdx.y * 128, DFF, hid, nullptr);
}

__global__ __launch_bounds__(256) void ffn2_k(const u16* __restrict__ hid,
                                              const u16* __restrict__ W2b,
                                              float* __restrict__ Out) {
  gemm_tile<2>(hid, W2b, DFF, blockIdx.x * 128, blockIdx.y * 128, DV, nullptr, Out);
}

// ---------------- single-pass flash attention ----------------
// 512 blocks = (b,h,128-row q-tile); 8 waves, each owns a 16-row stripe.
// K,V^T,P in LDS, power-of-2 strides + XOR-slot swizzle applied on both sides.
// Staging duties wave-split: waves 0-4 stage K, waves 5-7 build V^T.
__global__ __launch_bounds__(512) void attn_k(const u16* __restrict__ Qb,
                                              const u16* __restrict__ Kb,
                                              const u16* __restrict__ Vb,
                                              u16* __restrict__ Ob,
                                              float* __restrict__ Out) {
  __shared__ __align__(16) u16 Kl[128 * 64];    // [k-row][64 d-cols], swizzled, 16KB
  __shared__ __align__(16) u16 VTl[48 * 128];   // [d][k], swizzled, 12KB
  __shared__ __align__(16) u16 Pl[128 * 128];   // [q][k], swizzled, 32KB (Q scratch first)

  int bx0 = blockIdx.x;
  int lg = (bx0 & 7) * 64 + (bx0 >> 3);         // XCD swizzle (512 = 8*64, bijective)
  int qt = lg & 15, h = (lg >> 4) & 7, b = lg >> 7;
  const int t = threadIdx.x, l = t & 63, w = t >> 6;
  const int g = l >> 4, n = l & 15;
  const long rowbase = (long)b * NSEQ;
  const int q0 = qt * QBLK;
  const int hc = h * DH;

  // ---- stage scaled Q into Pl scratch (unswizzled [128][64]) + zero pads
  for (int i = t; i < 768; i += 512) {
    int r = i / 6, ch = i - r * 6;
    bf16x8 v = *(const bf16x8*)(Qb + (rowbase + q0 + r) * DV + hc + ch * 8);
    bf16x8 sv;
#pragma unroll
    for (int e = 0; e < 8; ++e) sv[e] = (short)f2bf(bf2f((u16)v[e]) * SCALE);
    *(bf16x8*)(Pl + r * 64 + ch * 8) = sv;
  }
  if (t < 256) {
    int r = t >> 1;
    bf16x8 z = {};
    *(bf16x8*)(Pl + r * 64 + 48 + (t & 1) * 8) = z;
  }
  if (t < 256) {  // zero Kl pad slots (raw slots 6,7 at swizzled positions) — once
    int r = t >> 1; int zs = 6 + (t & 1);
    bf16x8 z = {};
    *(bf16x8*)(Kl + r * 64 + ((zs ^ (r & 7)) * 8)) = z;
  }
  __syncthreads();

  // per-wave Q fragments (A-frag: row = stripe-local q = n, k = 32ks + 8g)
  bf16x8 qa[2];
#pragma unroll
  for (int ks = 0; ks < 2; ++ks)
    qa[ks] = *(const bf16x8*)(Pl + (w * 16 + n) * 64 + ks * 32 + g * 8);

  float mL[4], sL[4];
#pragma unroll
  for (int jr = 0; jr < 4; ++jr) { mL[jr] = -1e30f; sL[jr] = 0.0f; }
  f32x4 oacc[3] = {};

  for (int c = 0; c < 16; ++c) {
    __syncthreads();   // prev chunk LDS reads done (also protects qa/Pl scratch on c=0)
    if (t < 320) {
      // waves 0-4: stage K chunk (128 rows x 48 cols), swizzled slots
      for (int i = t; i < 768; i += 320) {
        int r = i / 6, ch = i - r * 6;
        bf16x8 v = *(const bf16x8*)(Kb + (rowbase + c * 128 + r) * DV + hc + ch * 8);
        *(bf16x8*)(Kl + r * 64 + ((ch ^ (r & 7)) * 8)) = v;
      }
    } else {
      // waves 5-7 (192 threads): stage V transposed, 4-row short4 packs, swizzled
      int j = t - 320;
      int q = j & 31, ch = j >> 5;    // q: 4-row pack, ch: col chunk of 8
      const u16* vbase = Vb + (rowbase + c * 128 + 4 * q) * DV + hc + ch * 8;
      bf16x8 v0 = *(const bf16x8*)(vbase);
      bf16x8 v1 = *(const bf16x8*)(vbase + DV);
      bf16x8 v2 = *(const bf16x8*)(vbase + 2 * DV);
      bf16x8 v3 = *(const bf16x8*)(vbase + 3 * DV);
#pragma unroll
      for (int e = 0; e < 8; ++e) {
        short4 pk; pk.x = v0[e]; pk.y = v1[e]; pk.z = v2[e]; pk.w = v3[e];
        int d = ch * 8 + e;
        *(short4*)(VTl + ((d * 128 + 4 * q) ^ (e << 3))) = pk;
      }
    }
    __syncthreads();

    // QK^T: wave computes its 16 q-rows x 128 k-cols (8 jl tiles)
    f32x4 sc[8];
#pragma unroll
    for (int jl = 0; jl < 8; ++jl) {
      f32x4 a = {};
#pragma unroll
      for (int ks = 0; ks < 2; ++ks) {
        bf16x8 kb = *(const bf16x8*)(Kl + (jl * 16 + n) * 64 + (((ks * 4 + g) ^ (n & 7)) * 8));
        a = __builtin_amdgcn_mfma_f32_16x16x32_bf16(qa[ks], kb, a, 0, 0, 0);
      }
      sc[jl] = a;
    }

    // online softmax (rows 4g+jr), P->LDS (bf16, swizzled), O rescale
#pragma unroll
    for (int jr = 0; jr < 4; ++jr) {
      float mx = sc[0][jr];
#pragma unroll
      for (int jl = 1; jl < 8; ++jl) mx = fmaxf(mx, sc[jl][jr]);
      mx = fmaxf(mx, __shfl_xor(mx, 1, 64));
      mx = fmaxf(mx, __shfl_xor(mx, 2, 64));
      mx = fmaxf(mx, __shfl_xor(mx, 4, 64));
      mx = fmaxf(mx, __shfl_xor(mx, 8, 64));
      float mn = fmaxf(mL[jr], mx);
      float scl = __expf(mL[jr] - mn);
      mL[jr] = mn;
      float rs = 0.0f;
      const int prow = w * 16 + 4 * g + jr;
      const int pswz = ((4 * g + jr) & 7) << 3;
#pragma unroll
      for (int jl = 0; jl < 8; ++jl) {
        float p = __expf(sc[jl][jr] - mn);
        rs += p;
        Pl[(prow * 128 + jl * 16 + n) ^ pswz] = f2bf(p);
      }
      rs += __shfl_xor(rs, 1, 64);
      rs += __shfl_xor(rs, 2, 64);
      rs += __shfl_xor(rs, 4, 64);
      rs += __shfl_xor(rs, 8, 64);
      sL[jr] = sL[jr] * scl + rs;
#pragma unroll
      for (int dt = 0; dt < 3; ++dt) oacc[dt][jr] *= scl;
    }

    // PV: own-wave P rows (lgkmcnt dependency, no barrier needed)
#pragma unroll
    for (int ks4 = 0; ks4 < 4; ++ks4) {
      const int slot = ((ks4 * 4 + g) ^ (n & 7)) * 8;
      bf16x8 pa = *(const bf16x8*)(Pl + (w * 16 + n) * 128 + slot);
#pragma unroll
      for (int dt = 0; dt < 3; ++dt) {
        bf16x8 vb = *(const bf16x8*)(VTl + (dt * 16 + n) * 128 + slot);
        oacc[dt] = __builtin_amdgcn_mfma_f32_16x16x32_bf16(pa, vb, oacc[dt], 0, 0, 0);
      }
    }
  }

  // epilogue: normalize, add (unscaled) Q residual, write f32 + bf16
#pragma unroll
  for (int jr = 0; jr < 4; ++jr) {
    float inv = 1.0f / sL[jr];
    long gr = rowbase + q0 + w * 16 + 4 * g + jr;
#pragma unroll
    for (int dt = 0; dt < 3; ++dt) {
      int col = hc + dt * 16 + n;
      float val = oacc[dt][jr] * inv;
      float q = bf2f(Qb[gr * DV + col]);
      float o = q + val;
      Out[gr * DV + col] = o;
      Ob[gr * DV + col] = f2bf(o);
    }
  }
}

// ---------------- launcher ----------------
extern "C" void kernel_launch(void* const* d_in, const int* in_sizes, int n_in,
                              void* d_out, int out_size, void* d_ws, size_t ws_size,
                              hipStream_t stream) {
  const float* xf = (const float*)d_in[0];
  const float* yf = (const float*)d_in[1];
  const float* wq = (const float*)d_in[2];
  const float* wk = (const float*)d_in[3];
  const float* wv = (const float*)d_in[4];
  const float* w1 = (const float*)d_in[5];
  const float* w2 = (const float*)d_in[6];
  float* Out = (float*)d_out;

  char* ws = (char*)d_ws;
  u16* xb   = (u16*)(ws + 0);          // 6291456
  u16* yb   = (u16*)(ws + 6291456);    // 6291456
  u16* QKVb = (u16*)(ws + 12582912);   // Q,K,V contiguous, 3*6291456
  u16* Qb   = QKVb;
  u16* Kb   = (u16*)(ws + 18874368);
  u16* Vb   = (u16*)(ws + 25165824);
  u16* Ob   = (u16*)(ws + 31457280);   // 6291456
  u16* Wqb  = (u16*)(ws + 37748736);   // 294912*3 (Wq,Wk,Wv contiguous)
  u16* W1b  = (u16*)(ws + 38633472);   // 1179648
  u16* W2b  = (u16*)(ws + 39813120);   // 1179648
  u16* hid  = (u16*)(ws + 0);          // 25165824, aliases xb/yb/Qb/Kb (dead by FFN1)
  u16* Wkb  = (u16*)(ws + 38043648);
  u16* Wvb  = (u16*)(ws + 38338560);

  convert_k<<<7728, 256, 0, stream>>>(xf, yf, wq, wk, wv, w1, w2,
                                      xb, yb, Wqb, Wkb, Wvb, W1b, W2b);
  qkv_k<<<dim3(64, 9), 256, 0, stream>>>(xb, yb, Wqb, QKVb);
  attn_k<<<512, 512, 0, stream>>>(Qb, Kb, Vb, Ob, Out);
  ffn1_k<<<dim3(64, 12), 256, 0, stream>>>(Ob, W1b, hid);
  ffn2_k<<<dim3(64, 3), 256, 0, stream>>>(hid, W2b, Out);
}